// Round 1
// baseline (444.188 us; speedup 1.0000x reference)
//
#include <hip/hip_runtime.h>

// Problem constants
#define NB   16
#define CD   512     // C
#define HW0  3136    // HW (valid)
#define HWP  3328    // HW padded to multiple of 256 (13*256)
#define DD   512     // D

typedef _Float16 half8 __attribute__((ext_vector_type(8)));
typedef _Float16 half2v __attribute__((ext_vector_type(2)));
typedef float    floatx4 __attribute__((ext_vector_type(4)));

// ---------------------------------------------------------------------------
// async global->LDS, 16B per lane. LDS dst is wave-uniform base + lane*16.
__device__ __forceinline__ void load_lds16(const _Float16* g, _Float16* l) {
    __builtin_amdgcn_global_load_lds(
        (__attribute__((address_space(1))) void*)g,
        (__attribute__((address_space(3))) void*)l,
        16, 0, 0);
}

// ---------------------------------------------------------------------------
// transpose + cast: batch_flat [N, C, HW] fp32 -> Xt [N, HWP, C] fp16
// tile 64(hw) x 128(c). 3136 = 49*64 so validity is block-uniform
// (tiles x=49..51 are all pad -> zeros).
__global__ __launch_bounds__(256) void transpose_cast_kernel(
        const float* __restrict__ in, _Float16* __restrict__ out) {
    __shared__ float tile[128][65];
    const int n  = blockIdx.z;
    const int h0 = blockIdx.x * 64;
    const int c0 = blockIdx.y * 128;
    const int t    = threadIdx.x;
    const int lane = t & 63;
    const int w    = t >> 6;           // wave 0..3
    const int rsub = lane >> 4;        // 0..3
    const int col4 = (lane & 15) * 4;  // 0..60 (16B-aligned)
    const float* src = in + (long long)n * CD * HW0 + (long long)c0 * HW0 + h0;
    const bool valid = h0 < HW0;       // block-uniform

    float4 r[8];
    if (valid) {
#pragma unroll
        for (int j = 0; j < 8; j++) {
            const int row = w * 32 + j * 4 + rsub;   // c-row 0..127
            r[j] = *(const float4*)(src + (long long)row * HW0 + col4);
        }
    } else {
#pragma unroll
        for (int j = 0; j < 8; j++) r[j] = make_float4(0.f, 0.f, 0.f, 0.f);
    }
#pragma unroll
    for (int j = 0; j < 8; j++) {
        const int row = w * 32 + j * 4 + rsub;
        tile[row][col4 + 0] = r[j].x;
        tile[row][col4 + 1] = r[j].y;
        tile[row][col4 + 2] = r[j].z;
        tile[row][col4 + 3] = r[j].w;
    }
    __syncthreads();
    _Float16* dst = out + (long long)n * HWP * CD + (long long)h0 * CD + c0;
#pragma unroll
    for (int j = 0; j < 16; j++) {
        const int i = w * 16 + j;      // hw-row 0..63
        half2v v = { (_Float16)tile[2 * lane][i], (_Float16)tile[2 * lane + 1][i] };
        *(half2v*)(dst + (long long)i * CD + 2 * lane) = v;
    }
}

// ---------------------------------------------------------------------------
// weight/bias conversion: Wq,Wk -> W2 [1024,512] fp16; Wv -> Wvh [512,512] fp16
__global__ void convert_w_kernel(const float* __restrict__ wq, const float* __restrict__ wk,
                                 const float* __restrict__ wv, const float* __restrict__ bq,
                                 const float* __restrict__ bk,
                                 _Float16* __restrict__ w2, _Float16* __restrict__ wvh,
                                 float* __restrict__ b2) {
    int i = blockIdx.x * 256 + threadIdx.x;
    if (i < CD * DD) {
        w2[i]           = (_Float16)wq[i];
        w2[CD * DD + i] = (_Float16)wk[i];
        wvh[i]          = (_Float16)wv[i];
    }
    if (i < DD) { b2[i] = bq[i]; b2[DD + i] = bk[i]; }
}

// ---------------------------------------------------------------------------
// 256x256 8-phase deep-pipelined MFMA GEMM (B^T convention, lda == K).
// T2: XOR LDS swizzle (16B slot ^= row&7) applied on BOTH sides: pre-swizzled
//     global source for global_load_lds (LDS stays linear) + swizzled ds_read.
// T3/T4: 8 phases / 2 K-tiles, one half-tile (128x64) staged per phase,
//     counted s_waitcnt vmcnt(4) only twice per 8 phases (vmcnt(0) only at
//     the final tile boundary). Raw s_barrier (no compiler vmcnt(0) drain).
// T5: s_setprio(1) around each 16-MFMA cluster.
//
// Schedule (iteration i, tiles T=2i in buf0 phases0-3, T+1 in buf1 phases4-7;
// local phase q reads A-half(q>>1), B-half(q&1)):
//   p0: stage A1(T+1)   p1: B1(T+1)   p2: A0(T+2)   p3: B0(T+2) +vmcnt(4)
//   p4: stage A1(T+2)   p5: B1(T+2)   p6: A0(T+3)   p7: B0(T+3) +vmcnt(4)
// Each stage targets a region whose last reader finished >=1 barrier earlier;
// each region is waited on (FIFO vmcnt) >=2 phases after its stage issue.
template <int BIAS_MODE, bool OUT_HALF, bool ZERO_PAD, int GX, int GY, int ORDER>
__global__ __launch_bounds__(512, 2)
void gemm256(const _Float16* __restrict__ A, const _Float16* __restrict__ B,
             void* __restrict__ Cout, const float* __restrict__ bias,
             int K, int nValid, int ldc,
             long long strideA, long long strideB, long long strideC) {
    __shared__ _Float16 sA[2][256 * 64];
    __shared__ _Float16 sB[2][256 * 64];

    const int tid  = threadIdx.x;
    const int wave = tid >> 6;
    const int lane = tid & 63;

    const int G = gridDim.x;               // divisible by 8
    const int bb = blockIdx.x;
    const int w = (bb & 7) * (G >> 3) + (bb >> 3);   // XCD-chunked swizzle
    int bx, by, bz;
    if (ORDER == 0) { bx = w % GX; int r = w / GX; by = r % GY; bz = r / GY; }
    else            { by = w % GY; int r = w / GY; bx = r % GX; bz = r / GX; }

    const int m0 = bx * 256, n0 = by * 256;
    const _Float16* Ab = A + (long long)bz * strideA + (long long)m0 * K;
    const _Float16* Bb = B + (long long)bz * strideB + (long long)n0 * K;

    const int NT = K >> 6;    // K-tiles of 64
    const int NI = NT >> 1;   // main iterations (2 tiles each)

    // ---- staging constants: thread t, load j covers LDS bytes
    // t*16 + j*8192 of a 128x64 half-tile => row r=(t>>3)+64j, 16B-slot t&7.
    // Source slot is pre-swizzled: s' = (t&7) ^ (r&7)  (r&7 == (t>>3)&7).
    const int sr  = tid >> 3;
    const long long goff  = (long long)sr * K + (((tid & 7) ^ (sr & 7)) << 3);
    const long long goff2 = goff + ((long long)K << 6);   // +64 rows

#define STG_A(buf, h, kt) if ((kt) < NT) {                                    \
        const _Float16* g = Ab + ((long long)(h) * 128) * K + ((kt) << 6);    \
        load_lds16(g + goff,  sA[buf] + (h) * 8192 + tid * 8);                \
        load_lds16(g + goff2, sA[buf] + (h) * 8192 + tid * 8 + 4096); }
#define STG_B(buf, h, kt) if ((kt) < NT) {                                    \
        const _Float16* g = Bb + ((long long)(h) * 128) * K + ((kt) << 6);    \
        load_lds16(g + goff,  sB[buf] + (h) * 8192 + tid * 8);                \
        load_lds16(g + goff2, sB[buf] + (h) * 8192 + tid * 8 + 4096); }

    // ---- fragment-read constants (swizzled ds_read):
    // logical slot (kk*4 + (lane>>4)) ^ (row&7); row&7 == lane&7.
    const int frow = lane & 15;
    const int so0  = ((((lane >> 4) ^ lane) & 7) << 3);   // halfs
    const int so1  = so0 ^ 32;

    floatx4 acc[2][2][4][2];
#pragma unroll
    for (int q0 = 0; q0 < 2; q0++)
#pragma unroll
        for (int q1 = 0; q1 < 2; q1++)
#pragma unroll
            for (int q2 = 0; q2 < 4; q2++)
#pragma unroll
                for (int q3 = 0; q3 < 2; q3++) acc[q0][q1][q2][q3] = (floatx4)0.0f;

#define MM(MH, NH, I, J, A0_, A1_, B0_, B1_)                                              \
    acc[MH][NH][I][J] = __builtin_amdgcn_mfma_f32_16x16x32_f16(A0_, B0_, acc[MH][NH][I][J], 0, 0, 0); \
    acc[MH][NH][I][J] = __builtin_amdgcn_mfma_f32_16x16x32_f16(A1_, B1_, acc[MH][NH][I][J], 0, 0, 0);

#define PHASE(BUF, MH, NH, STAGE, TAIL) {                                                 \
    const _Float16* aB = sA[BUF] + ((wave >> 2) * 64 + (MH) * 128 + frow) * 64;           \
    const _Float16* bB = sB[BUF] + ((wave & 3) * 32 + (NH) * 128 + frow) * 64;            \
    half8 a00 = *(const half8*)(aB +    0 + so0);                                         \
    half8 a01 = *(const half8*)(aB +    0 + so1);                                         \
    half8 a10 = *(const half8*)(aB + 1024 + so0);                                         \
    half8 a11 = *(const half8*)(aB + 1024 + so1);                                         \
    half8 a20 = *(const half8*)(aB + 2048 + so0);                                         \
    half8 a21 = *(const half8*)(aB + 2048 + so1);                                         \
    half8 a30 = *(const half8*)(aB + 3072 + so0);                                         \
    half8 a31 = *(const half8*)(aB + 3072 + so1);                                         \
    half8 b0l = *(const half8*)(bB +    0 + so0);                                         \
    half8 b0h = *(const half8*)(bB +    0 + so1);                                         \
    half8 b1l = *(const half8*)(bB + 1024 + so0);                                         \
    half8 b1h = *(const half8*)(bB + 1024 + so1);                                         \
    STAGE;                                                                                \
    asm volatile("s_barrier" ::: "memory");                                               \
    __builtin_amdgcn_s_setprio(1);                                                        \
    MM(MH, NH, 0, 0, a00, a01, b0l, b0h)                                                  \
    MM(MH, NH, 0, 1, a00, a01, b1l, b1h)                                                  \
    MM(MH, NH, 1, 0, a10, a11, b0l, b0h)                                                  \
    MM(MH, NH, 1, 1, a10, a11, b1l, b1h)                                                  \
    MM(MH, NH, 2, 0, a20, a21, b0l, b0h)                                                  \
    MM(MH, NH, 2, 1, a20, a21, b1l, b1h)                                                  \
    MM(MH, NH, 3, 0, a30, a31, b0l, b0h)                                                  \
    MM(MH, NH, 3, 1, a30, a31, b1l, b1h)                                                  \
    __builtin_amdgcn_s_setprio(0);                                                        \
    TAIL;                                                                                 \
    asm volatile("s_barrier" ::: "memory");                                               \
}

#define VM_NONE   {}
#define VM_TAIL34 { if (i + 1 < NI) asm volatile("s_waitcnt vmcnt(4)" ::: "memory");      \
                    else            asm volatile("s_waitcnt vmcnt(0)" ::: "memory"); }
#define VM_TAIL78 { if (i + 1 < NI) asm volatile("s_waitcnt vmcnt(4)" ::: "memory"); }

    // prologue: tile0 fully (A0,B0,A1,B1) + tile1 A0,B0 -> 12 loads in flight;
    // wait for tile0 (oldest 8), keep 4 outstanding.
    STG_A(0, 0, 0); STG_B(0, 0, 0); STG_A(0, 1, 0); STG_B(0, 1, 0);
    STG_A(1, 0, 1); STG_B(1, 0, 1);
    asm volatile("s_waitcnt vmcnt(4)" ::: "memory");
    asm volatile("s_barrier" ::: "memory");

    for (int i = 0; i < NI; i++) {
        const int T = 2 * i;
        PHASE(0, 0, 0, STG_A(1, 1, T + 1), VM_NONE)
        PHASE(0, 0, 1, STG_B(1, 1, T + 1), VM_NONE)
        PHASE(0, 1, 0, STG_A(0, 0, T + 2), VM_NONE)
        PHASE(0, 1, 1, STG_B(0, 0, T + 2), VM_TAIL34)
        PHASE(1, 0, 0, STG_A(0, 1, T + 2), VM_NONE)
        PHASE(1, 0, 1, STG_B(0, 1, T + 2), VM_NONE)
        PHASE(1, 1, 0, STG_A(1, 0, T + 3), VM_NONE)
        PHASE(1, 1, 1, STG_B(1, 0, T + 3), VM_TAIL78)
    }
#undef PHASE
#undef MM
#undef STG_A
#undef STG_B
#undef VM_NONE
#undef VM_TAIL34
#undef VM_TAIL78

    // epilogue: C/D layout col = lane&15, row = (lane>>4)*4 + reg
    const int erow = (lane >> 4) * 4;
    const int ecol = lane & 15;
#pragma unroll
    for (int mh = 0; mh < 2; mh++) {
#pragma unroll
        for (int it = 0; it < 4; it++) {
#pragma unroll
            for (int r = 0; r < 4; r++) {
                const int row = m0 + mh * 128 + (wave >> 2) * 64 + it * 16 + erow + r;
#pragma unroll
                for (int nh = 0; nh < 2; nh++) {
#pragma unroll
                    for (int j = 0; j < 2; j++) {
                        const int col = n0 + nh * 128 + (wave & 3) * 32 + j * 16 + ecol;
                        float v = acc[mh][nh][it][j][r];
                        if (BIAS_MODE == 1) v += bias[row];
                        if (BIAS_MODE == 2) v += bias[col];
                        const bool valid = (col < nValid);
                        const long long idx =
                            (long long)bz * strideC + (long long)row * ldc + col;
                        if (OUT_HALF) {
                            if (ZERO_PAD) {
                                ((_Float16*)Cout)[idx] = (_Float16)(valid ? v : 0.f);
                            } else if (valid) {
                                ((_Float16*)Cout)[idx] = (_Float16)v;
                            }
                        } else {
                            if (ZERO_PAD) {
                                ((float*)Cout)[idx] = valid ? v : 0.f;
                            } else if (valid) {
                                ((float*)Cout)[idx] = v;
                            }
                        }
                    }
                }
            }
        }
    }
}

// ---------------------------------------------------------------------------
// scores GEMM, split-K=2 for occupancy (512 blocks -> 2 blocks/CU instead of
// 1): S_part[part][n][d][e] = sum_{s in half} Q[d][s]*K[e][s].
// 128^2 tile, BK=32 (m97-class structure; K panels are lda=HWP).
__global__ __launch_bounds__(256, 2)
void gemm_scores(const _Float16* __restrict__ QK, float* __restrict__ S) {
    constexpr int BK = 32;
    constexpr int KH = HWP / 2;          // 1664
    __shared__ _Float16 As[128 * BK];
    __shared__ _Float16 Bs[128 * BK];

    const int tid  = threadIdx.x;
    const int wave = tid >> 6;
    const int lane = tid & 63;

    const int G = gridDim.x;             // 512
    const int b = blockIdx.x;
    const int w = (b & 7) * (G >> 3) + (b >> 3);
    const int bx = w & 3;                // GX=4 (d), x fastest
    const int by = (w >> 2) & 3;         // GY=4 (e)
    const int zz = w >> 4;               // 0..31
    const int part = zz & 1;
    const int n    = zz >> 1;

    const int m0 = bx * 128, n0 = by * 128;
    const _Float16* Ab = QK + (long long)n * (2LL * DD * HWP) + (long long)part * KH;
    const _Float16* Bb = Ab + (long long)DD * HWP;

    const int srow = lane >> 2;
    const int scol = (lane & 3) * 8;
    const _Float16* ga0 = Ab + (long long)(m0 + wave * 32 + srow) * HWP + scol;
    const _Float16* ga1 = ga0 + (long long)16 * HWP;
    const _Float16* gb0 = Bb + (long long)(n0 + wave * 32 + srow) * HWP + scol;
    const _Float16* gb1 = gb0 + (long long)16 * HWP;
    _Float16* lA0 = As + (wave * 32) * BK;
    _Float16* lA1 = As + (wave * 32 + 16) * BK;
    _Float16* lB0 = Bs + (wave * 32) * BK;
    _Float16* lB1 = Bs + (wave * 32 + 16) * BK;

    floatx4 acc[4][4];
#pragma unroll
    for (int i = 0; i < 4; i++)
#pragma unroll
        for (int j = 0; j < 4; j++) acc[i][j] = (floatx4)0.0f;

    const int wm = (wave >> 1) * 64, wn = (wave & 1) * 64;
    const int frow = lane & 15;
    const int fk   = (lane >> 4) * 8;

    for (int k0 = 0; k0 < KH; k0 += BK) {
        load_lds16(ga0, lA0); load_lds16(ga1, lA1);
        load_lds16(gb0, lB0); load_lds16(gb1, lB1);
        ga0 += BK; ga1 += BK; gb0 += BK; gb1 += BK;
        __syncthreads();

        half8 af[4], bf[4];
#pragma unroll
        for (int t = 0; t < 4; t++)
            af[t] = *(const half8*)(As + (wm + t * 16 + frow) * BK + fk);
#pragma unroll
        for (int t = 0; t < 4; t++)
            bf[t] = *(const half8*)(Bs + (wn + t * 16 + frow) * BK + fk);
#pragma unroll
        for (int mt = 0; mt < 4; mt++)
#pragma unroll
            for (int nt = 0; nt < 4; nt++)
                acc[mt][nt] = __builtin_amdgcn_mfma_f32_16x16x32_f16(
                    af[mt], bf[nt], acc[mt][nt], 0, 0, 0);
        __syncthreads();
    }

    const int erow = (lane >> 4) * 4;
    const int ecol = lane & 15;
    float* Sb = S + (long long)part * (16LL * DD * DD) + (long long)n * DD * DD;
#pragma unroll
    for (int mt = 0; mt < 4; mt++)
#pragma unroll
        for (int r = 0; r < 4; r++) {
            const int row = m0 + wm + mt * 16 + erow + r;
#pragma unroll
            for (int nt = 0; nt < 4; nt++) {
                const int col = n0 + wn + nt * 16 + ecol;
                Sb[(long long)row * DD + col] = acc[mt][nt][r];
            }
        }
}

// ---------------------------------------------------------------------------
// row softmax over split-K partial sums: att = softmax(S0+S1), one wave/row
__global__ void softmax_kernel(const float* __restrict__ S, _Float16* __restrict__ att) {
    const int row  = blockIdx.x * 4 + (threadIdx.x >> 6);
    const int lane = threadIdx.x & 63;
    const float* s0 = S + (long long)row * DD;
    const float* s1 = s0 + 16LL * DD * DD;
    float v[8];
#pragma unroll
    for (int i = 0; i < 8; i++) v[i] = s0[lane + i * 64] + s1[lane + i * 64];
    float m = v[0];
#pragma unroll
    for (int i = 1; i < 8; i++) m = fmaxf(m, v[i]);
#pragma unroll
    for (int off = 32; off; off >>= 1) m = fmaxf(m, __shfl_xor(m, off, 64));
    float s = 0.f;
#pragma unroll
    for (int i = 0; i < 8; i++) { v[i] = __expf(v[i] - m); s += v[i]; }
#pragma unroll
    for (int off = 32; off; off >>= 1) s += __shfl_xor(s, off, 64);
    const float inv = 1.0f / s;
    _Float16* dst = att + (long long)row * DD;
#pragma unroll
    for (int i = 0; i < 8; i++) dst[lane + i * 64] = (_Float16)(v[i] * inv);
}

// ---------------------------------------------------------------------------
extern "C" void kernel_launch(void* const* d_in, const int* in_sizes, int n_in,
                              void* d_out, int out_size, void* d_ws, size_t ws_size,
                              hipStream_t stream) {
    const float* batch = (const float*)d_in[0];
    const float* Wq = (const float*)d_in[1];
    const float* bq = (const float*)d_in[2];
    const float* Wk = (const float*)d_in[3];
    const float* bk = (const float*)d_in[4];
    const float* Wv = (const float*)d_in[5];
    const float* bv = (const float*)d_in[6];

    char* ws = (char*)d_ws;
    const long long XT_B  = (long long)NB * HWP * CD * 2;      // 54,525,952
    const long long QKT_B = (long long)NB * 2 * DD * HWP * 2;  // 109,051,904
    const long long VS_B  = (long long)NB * HWP * DD * 2;      // 54,525,952
    const long long W2_B  = (long long)2 * DD * CD * 2;        // 1,048,576
    const long long WVH_B = (long long)DD * CD * 2;            // 524,288

    _Float16* Xt  = (_Float16*)(ws);
    _Float16* QKt = (_Float16*)(ws + XT_B);
    _Float16* Vs  = (_Float16*)(ws + XT_B + QKT_B);
    _Float16* W2  = (_Float16*)(ws + XT_B + QKT_B + VS_B);
    _Float16* Wvh = (_Float16*)(ws + XT_B + QKT_B + VS_B + W2_B);
    float*    b2  = (float*)   (ws + XT_B + QKT_B + VS_B + W2_B + WVH_B);
    // S (2 split-K parts, 33.6MB) and att alias the Xt region (dead after V)
    float*    S   = (float*)(ws);
    _Float16* att = (_Float16*)(ws + 2LL * NB * DD * DD * 4);  // ws + 33,554,432

    // 1) weights/bias -> fp16
    convert_w_kernel<<<dim3((CD * DD + 255) / 256), dim3(256), 0, stream>>>(
        Wq, Wk, Wv, bq, bk, W2, Wvh, b2);

    // 2) batch_flat [N,C,HW] fp32 -> Xt [N,HWP,C] fp16 (zero-padded rows)
    transpose_cast_kernel<<<dim3(HWP / 64, CD / 128, NB), dim3(256), 0, stream>>>(
        batch, Xt);

    // 3) QK projection: QKt[n][m][s] = sum_c W2[m][c]*Xt[n][s][c] + b2[m]
    //    256^2 8-phase kernel; GX=4 (m), GY=13 (s), x fastest shares Xt tile.
    gemm256<1, true, true, 4, 13, 0><<<dim3(4 * 13 * NB), dim3(512), 0, stream>>>(
        W2, Xt, (void*)QKt, b2, CD, HW0, HWP,
        0LL, (long long)HWP * CD, (long long)2 * DD * HWP);

    // 4) V projection: Vs[n][s][e] = sum_c Xt[n][s][c]*Wv[e][c] + bv[e]
    //    GX=13 (s), GY=2 (e), y fastest shares Xt tile.
    gemm256<2, true, false, 13, 2, 1><<<dim3(13 * 2 * NB), dim3(512), 0, stream>>>(
        Xt, Wvh, (void*)Vs, bv, CD, DD, DD,
        (long long)HWP * CD, 0LL, (long long)HWP * DD);

    // 5) scores split-K=2: S[part][n][d][e] = sum_{s half} Qt[d][s]*Kt[e][s]
    gemm_scores<<<dim3(4 * 4 * NB * 2), dim3(256), 0, stream>>>(QKt, S);

    // 6) softmax rows (sums the two partials) -> att fp16
    softmax_kernel<<<dim3(NB * DD / 4), dim3(256), 0, stream>>>(S, att);

    // 7) out[n][d][s] = sum_e att[d][e]*Vs[n][s][e] -> d_out [N,D,HW] fp32
    //    GX=2 (d), GY=13 (s), x fastest shares Vs tile.
    gemm256<0, false, false, 2, 13, 0><<<dim3(2 * 13 * NB), dim3(512), 0, stream>>>(
        att, Vs, d_out, nullptr, DD, HW0, HW0,
        (long long)DD * DD, (long long)HWP * DD, (long long)DD * HW0);
}

// Round 7
// 401.822 us; speedup vs baseline: 1.1054x; 1.1054x over previous
//
#include <hip/hip_runtime.h>

// Problem constants
#define NB   16
#define CD   512     // C
#define HW0  3136    // HW (valid)
#define HWP  3200    // HW padded to multiple of 128
#define DD   512     // D

typedef _Float16 half8 __attribute__((ext_vector_type(8)));
typedef _Float16 half2v __attribute__((ext_vector_type(2)));
typedef float    floatx4 __attribute__((ext_vector_type(4)));

// ---------------------------------------------------------------------------
// async global->LDS, 16B per lane. LDS dst is wave-uniform base + lane*16.
__device__ __forceinline__ void load_lds16(const _Float16* g, _Float16* l) {
    __builtin_amdgcn_global_load_lds(
        (__attribute__((address_space(1))) void*)g,
        (__attribute__((address_space(3))) void*)l,
        16, 0, 0);
}

// ---------------------------------------------------------------------------
// transpose + cast: batch_flat [N, C, HW] fp32 -> Xt [N, HWP, C] fp16
// tile 64(hw) x 128(c). 3136 = 49*64 so validity is block-uniform.
__global__ __launch_bounds__(256) void transpose_cast_kernel(
        const float* __restrict__ in, _Float16* __restrict__ out) {
    __shared__ float tile[128][65];
    const int n  = blockIdx.z;
    const int h0 = blockIdx.x * 64;
    const int c0 = blockIdx.y * 128;
    const int t    = threadIdx.x;
    const int lane = t & 63;
    const int w    = t >> 6;           // wave 0..3
    const int rsub = lane >> 4;        // 0..3
    const int col4 = (lane & 15) * 4;  // 0..60 (16B-aligned)
    const float* src = in + (long long)n * CD * HW0 + (long long)c0 * HW0 + h0;
    const bool valid = h0 < HW0;       // block-uniform

    float4 r[8];
    if (valid) {
#pragma unroll
        for (int j = 0; j < 8; j++) {
            const int row = w * 32 + j * 4 + rsub;   // c-row 0..127
            r[j] = *(const float4*)(src + (long long)row * HW0 + col4);
        }
    } else {
#pragma unroll
        for (int j = 0; j < 8; j++) r[j] = make_float4(0.f, 0.f, 0.f, 0.f);
    }
#pragma unroll
    for (int j = 0; j < 8; j++) {
        const int row = w * 32 + j * 4 + rsub;
        tile[row][col4 + 0] = r[j].x;
        tile[row][col4 + 1] = r[j].y;
        tile[row][col4 + 2] = r[j].z;
        tile[row][col4 + 3] = r[j].w;
    }
    __syncthreads();
    _Float16* dst = out + (long long)n * HWP * CD + (long long)h0 * CD + c0;
#pragma unroll
    for (int j = 0; j < 16; j++) {
        const int i = w * 16 + j;      // hw-row 0..63
        half2v v = { (_Float16)tile[2 * lane][i], (_Float16)tile[2 * lane + 1][i] };
        *(half2v*)(dst + (long long)i * CD + 2 * lane) = v;
    }
}

// ---------------------------------------------------------------------------
// weight/bias conversion: Wq,Wk -> W2 [1024,512] fp16; Wv -> Wvh [512,512] fp16
__global__ void convert_w_kernel(const float* __restrict__ wq, const float* __restrict__ wk,
                                 const float* __restrict__ wv, const float* __restrict__ bq,
                                 const float* __restrict__ bk,
                                 _Float16* __restrict__ w2, _Float16* __restrict__ wvh,
                                 float* __restrict__ b2) {
    int i = blockIdx.x * 256 + threadIdx.x;
    if (i < CD * DD) {
        w2[i]           = (_Float16)wq[i];
        w2[CD * DD + i] = (_Float16)wk[i];
        wvh[i]          = (_Float16)wv[i];
    }
    if (i < DD) { b2[i] = bq[i]; b2[DD + i] = bk[i]; }
}

// ---------------------------------------------------------------------------
// Tiled MFMA GEMM, B^T convention: C[m][col] = sum_k A[m][k] * B[col][k]
// Round-0 proven body + T2 XOR swizzle:
//   LDS tiles are [128][BK=32] fp16 = 64B rows = 4 x 16B slots.
//   Stage: lane l writes LDS row wave*32+(l>>2), slot l&3; global source slot
//   is pre-swizzled (l&3)^(srow&3) so LDS slot s of row r holds global slot
//   s^(r&3).  Fragment read of global slot q=lane>>4 reads LDS slot
//   q^(frow&3) (row&3 == frow&3 for every +16/+64 row offset used).
//   8-way bank conflict -> 2-way (free).
template <int BIAS_MODE, bool OUT_HALF, bool ZERO_PAD, int GX, int GY, int ORDER>
__global__ __launch_bounds__(256, 2)
void gemm_tn(const _Float16* __restrict__ A, const _Float16* __restrict__ B,
             void* __restrict__ Cout, const float* __restrict__ bias,
             int K, int nValid, int ldc,
             long long strideA, long long strideB, long long strideC) {
    constexpr int BM = 128, BN = 128, BK = 32;
    __shared__ _Float16 As[BM * BK];
    __shared__ _Float16 Bs[BN * BK];

    const int tid  = threadIdx.x;
    const int wave = tid >> 6;
    const int lane = tid & 63;

    const int G = gridDim.x;               // GX*GY*GZ, divisible by 8
    const int b = blockIdx.x;
    const int w = (b & 7) * (G >> 3) + (b >> 3);
    int bx, by, bz;
    if (ORDER == 0) { bx = w % GX; int r = w / GX; by = r % GY; bz = r / GY; }
    else            { by = w % GY; int r = w / GY; bx = r % GX; bz = r / GX; }

    const int m0 = bx * BM;
    const int n0 = by * BN;

    const _Float16* Ab = A + (long long)bz * strideA;
    const _Float16* Bb = B + (long long)bz * strideB;

    const int srow = lane >> 2;                         // 0..15
    const int ssw  = ((lane & 3) ^ (srow & 3)) * 8;     // swizzled source slot
    const _Float16* ga0 = Ab + (long long)(m0 + wave * 32 + srow) * K + ssw;
    const _Float16* ga1 = ga0 + (long long)16 * K;      // (srow+16)&3 == srow&3
    const _Float16* gb0 = Bb + (long long)(n0 + wave * 32 + srow) * K + ssw;
    const _Float16* gb1 = gb0 + (long long)16 * K;
    _Float16* lA0 = As + (wave * 32) * BK;
    _Float16* lA1 = As + (wave * 32 + 16) * BK;
    _Float16* lB0 = Bs + (wave * 32) * BK;
    _Float16* lB1 = Bs + (wave * 32 + 16) * BK;

    floatx4 acc[4][4];
#pragma unroll
    for (int i = 0; i < 4; i++)
#pragma unroll
        for (int j = 0; j < 4; j++) acc[i][j] = (floatx4)0.0f;

    const int wm = (wave >> 1) * 64, wn = (wave & 1) * 64;
    const int frow = lane & 15;                          // fragment row (m or n)
    const int fk   = (((lane >> 4) ^ frow) & 3) * 8;     // swizzled read slot

    for (int k0 = 0; k0 < K; k0 += BK) {
        load_lds16(ga0, lA0); load_lds16(ga1, lA1);
        load_lds16(gb0, lB0); load_lds16(gb1, lB1);
        ga0 += BK; ga1 += BK; gb0 += BK; gb1 += BK;
        __syncthreads();

        half8 af[4], bf[4];
#pragma unroll
        for (int t = 0; t < 4; t++)
            af[t] = *(const half8*)(As + (wm + t * 16 + frow) * BK + fk);
#pragma unroll
        for (int t = 0; t < 4; t++)
            bf[t] = *(const half8*)(Bs + (wn + t * 16 + frow) * BK + fk);
#pragma unroll
        for (int mt = 0; mt < 4; mt++)
#pragma unroll
            for (int nt = 0; nt < 4; nt++)
                acc[mt][nt] = __builtin_amdgcn_mfma_f32_16x16x32_f16(
                    af[mt], bf[nt], acc[mt][nt], 0, 0, 0);
        __syncthreads();
    }

    // epilogue: C/D layout col = lane&15, row = (lane>>4)*4 + reg
    const int erow = (lane >> 4) * 4;
    const int ecol = lane & 15;
#pragma unroll
    for (int mt = 0; mt < 4; mt++) {
#pragma unroll
        for (int r = 0; r < 4; r++) {
            const int row = m0 + wm + mt * 16 + erow + r;
#pragma unroll
            for (int nt = 0; nt < 4; nt++) {
                const int col = n0 + wn + nt * 16 + ecol;
                float v = acc[mt][nt][r];
                if (BIAS_MODE == 1) v += bias[row];
                if (BIAS_MODE == 2) v += bias[col];
                const bool valid = (col < nValid);
                const long long idx = (long long)bz * strideC + (long long)row * ldc + col;
                if (OUT_HALF) {
                    if (ZERO_PAD) {
                        ((_Float16*)Cout)[idx] = (_Float16)(valid ? v : 0.f);
                    } else if (valid) {
                        ((_Float16*)Cout)[idx] = (_Float16)v;
                    }
                } else {
                    if (ZERO_PAD) {
                        ((float*)Cout)[idx] = valid ? v : 0.f;
                    } else if (valid) {
                        ((float*)Cout)[idx] = v;
                    }
                }
            }
        }
    }
}

// ---------------------------------------------------------------------------
// scores GEMM, split-K=2 (512 blocks -> 2 blocks/CU):
// S_part[part][n][d][e] = sum_{s in half} Q[d][s]*K[e][s].  128^2 tile, BK=32,
// lda = HWP.  Same XOR swizzle as gemm_tn.  (Structure verified passing in an
// earlier round at HWP=3328; here KH = 1600.)
__global__ __launch_bounds__(256, 2)
void gemm_scores(const _Float16* __restrict__ QK, float* __restrict__ S) {
    constexpr int BK = 32;
    constexpr int KH = HWP / 2;          // 1600
    __shared__ _Float16 As[128 * BK];
    __shared__ _Float16 Bs[128 * BK];

    const int tid  = threadIdx.x;
    const int wave = tid >> 6;
    const int lane = tid & 63;

    const int G = gridDim.x;             // 512
    const int b = blockIdx.x;
    const int w = (b & 7) * (G >> 3) + (b >> 3);
    const int bx = w & 3;                // GX=4 (d), x fastest
    const int by = (w >> 2) & 3;         // GY=4 (e)
    const int zz = w >> 4;               // 0..31
    const int part = zz & 1;
    const int n    = zz >> 1;

    const int m0 = bx * 128, n0 = by * 128;
    const _Float16* Ab = QK + (long long)n * (2LL * DD * HWP) + (long long)part * KH;
    const _Float16* Bb = Ab + (long long)DD * HWP;

    const int srow = lane >> 2;
    const int ssw  = ((lane & 3) ^ (srow & 3)) * 8;
    const _Float16* ga0 = Ab + (long long)(m0 + wave * 32 + srow) * HWP + ssw;
    const _Float16* ga1 = ga0 + (long long)16 * HWP;
    const _Float16* gb0 = Bb + (long long)(n0 + wave * 32 + srow) * HWP + ssw;
    const _Float16* gb1 = gb0 + (long long)16 * HWP;
    _Float16* lA0 = As + (wave * 32) * BK;
    _Float16* lA1 = As + (wave * 32 + 16) * BK;
    _Float16* lB0 = Bs + (wave * 32) * BK;
    _Float16* lB1 = Bs + (wave * 32 + 16) * BK;

    floatx4 acc[4][4];
#pragma unroll
    for (int i = 0; i < 4; i++)
#pragma unroll
        for (int j = 0; j < 4; j++) acc[i][j] = (floatx4)0.0f;

    const int wm = (wave >> 1) * 64, wn = (wave & 1) * 64;
    const int frow = lane & 15;
    const int fk   = (((lane >> 4) ^ frow) & 3) * 8;

    for (int k0 = 0; k0 < KH; k0 += BK) {
        load_lds16(ga0, lA0); load_lds16(ga1, lA1);
        load_lds16(gb0, lB0); load_lds16(gb1, lB1);
        ga0 += BK; ga1 += BK; gb0 += BK; gb1 += BK;
        __syncthreads();

        half8 af[4], bf[4];
#pragma unroll
        for (int t = 0; t < 4; t++)
            af[t] = *(const half8*)(As + (wm + t * 16 + frow) * BK + fk);
#pragma unroll
        for (int t = 0; t < 4; t++)
            bf[t] = *(const half8*)(Bs + (wn + t * 16 + frow) * BK + fk);
#pragma unroll
        for (int mt = 0; mt < 4; mt++)
#pragma unroll
            for (int nt = 0; nt < 4; nt++)
                acc[mt][nt] = __builtin_amdgcn_mfma_f32_16x16x32_f16(
                    af[mt], bf[nt], acc[mt][nt], 0, 0, 0);
        __syncthreads();
    }

    const int erow = (lane >> 4) * 4;
    const int ecol = lane & 15;
    float* Sb = S + (long long)part * (16LL * DD * DD) + (long long)n * DD * DD;
#pragma unroll
    for (int mt = 0; mt < 4; mt++)
#pragma unroll
        for (int r = 0; r < 4; r++) {
            const int row = m0 + wm + mt * 16 + erow + r;
#pragma unroll
            for (int nt = 0; nt < 4; nt++) {
                const int col = n0 + wn + nt * 16 + ecol;
                Sb[(long long)row * DD + col] = acc[mt][nt][r];
            }
        }
}

// ---------------------------------------------------------------------------
// row softmax over split-K partial sums: att = softmax(S0+S1), one wave/row
__global__ void softmax_kernel(const float* __restrict__ S, _Float16* __restrict__ att) {
    const int row  = blockIdx.x * 4 + (threadIdx.x >> 6);
    const int lane = threadIdx.x & 63;
    const float* s0 = S + (long long)row * DD;
    const float* s1 = s0 + 16LL * DD * DD;
    float v[8];
#pragma unroll
    for (int i = 0; i < 8; i++) v[i] = s0[lane + i * 64] + s1[lane + i * 64];
    float m = v[0];
#pragma unroll
    for (int i = 1; i < 8; i++) m = fmaxf(m, v[i]);
#pragma unroll
    for (int off = 32; off; off >>= 1) m = fmaxf(m, __shfl_xor(m, off, 64));
    float s = 0.f;
#pragma unroll
    for (int i = 0; i < 8; i++) { v[i] = __expf(v[i] - m); s += v[i]; }
#pragma unroll
    for (int off = 32; off; off >>= 1) s += __shfl_xor(s, off, 64);
    const float inv = 1.0f / s;
    _Float16* dst = att + (long long)row * DD;
#pragma unroll
    for (int i = 0; i < 8; i++) dst[lane + i * 64] = (_Float16)(v[i] * inv);
}

// ---------------------------------------------------------------------------
extern "C" void kernel_launch(void* const* d_in, const int* in_sizes, int n_in,
                              void* d_out, int out_size, void* d_ws, size_t ws_size,
                              hipStream_t stream) {
    const float* batch = (const float*)d_in[0];
    const float* Wq = (const float*)d_in[1];
    const float* bq = (const float*)d_in[2];
    const float* Wk = (const float*)d_in[3];
    const float* bk = (const float*)d_in[4];
    const float* Wv = (const float*)d_in[5];
    const float* bv = (const float*)d_in[6];

    char* ws = (char*)d_ws;
    const long long XT_B  = (long long)NB * HWP * CD * 2;      // 52,428,800
    const long long QKT_B = (long long)NB * 2 * DD * HWP * 2;  // 104,857,600
    const long long VS_B  = (long long)NB * HWP * DD * 2;      // 52,428,800
    const long long W2_B  = (long long)2 * DD * CD * 2;        // 1,048,576
    const long long WVH_B = (long long)DD * CD * 2;            // 524,288

    _Float16* Xt  = (_Float16*)(ws);
    _Float16* QKt = (_Float16*)(ws + XT_B);
    _Float16* Vs  = (_Float16*)(ws + XT_B + QKT_B);
    _Float16* W2  = (_Float16*)(ws + XT_B + QKT_B + VS_B);
    _Float16* Wvh = (_Float16*)(ws + XT_B + QKT_B + VS_B + W2_B);
    float*    b2  = (float*)   (ws + XT_B + QKT_B + VS_B + W2_B + WVH_B);
    // S (2 split-K parts, 33.6MB) and att (8.4MB) alias the Xt region
    // (dead after the V projection); 41.9MB <= XT_B = 52.4MB.
    float*    S   = (float*)(ws);
    _Float16* att = (_Float16*)(ws + 2LL * NB * DD * DD * 4);  // ws + 33,554,432

    // 1) weights/bias -> fp16
    convert_w_kernel<<<dim3((CD * DD + 255) / 256), dim3(256), 0, stream>>>(
        Wq, Wk, Wv, bq, bk, W2, Wvh, b2);

    // 2) batch_flat [N,C,HW] fp32 -> Xt [N,HWP,C] fp16 (zero-padded rows)
    transpose_cast_kernel<<<dim3(HWP / 64, CD / 128, NB), dim3(256), 0, stream>>>(
        batch, Xt);

    // 3) QK projection: QKt[n][m][s] = sum_c W2[m][c]*Xt[n][s][c] + b2[m]
    gemm_tn<1, true, true, 8, 25, 0><<<dim3(8 * 25 * NB), dim3(256), 0, stream>>>(
        W2, Xt, (void*)QKt, b2, CD, HW0, HWP,
        0LL, (long long)HWP * CD, (long long)2 * DD * HWP);

    // 4) V projection: Vs[n][s][e] = sum_c Xt[n][s][c]*Wv[e][c] + bv[e]
    gemm_tn<2, true, false, 25, 4, 1><<<dim3(25 * 4 * NB), dim3(256), 0, stream>>>(
        Xt, Wvh, (void*)Vs, bv, CD, DD, DD,
        (long long)HWP * CD, 0LL, (long long)HWP * DD);

    // 5) scores split-K=2: S[part][n][d][e] = sum_{s in half} Qt[d][s]*Kt[e][s]
    gemm_scores<<<dim3(4 * 4 * NB * 2), dim3(256), 0, stream>>>(QKt, S);

    // 6) softmax rows (sums the two partials) -> att fp16
    softmax_kernel<<<dim3(NB * DD / 4), dim3(256), 0, stream>>>(S, att);

    // 7) out[n][d][s] = sum_e att[d][e]*Vs[n][s][e] -> d_out [N,D,HW] fp32
    gemm_tn<0, false, false, 4, 25, 0><<<dim3(4 * 25 * NB), dim3(256), 0, stream>>>(
        att, Vs, d_out, nullptr, DD, HW0, HW0,
        (long long)DD * DD, (long long)HWP * DD, (long long)DD * HW0);
}